// Round 6
// baseline (408.162 us; speedup 1.0000x reference)
//
#include <hip/hip_runtime.h>
#include <cmath>

#define NH 16
#define NKV 4
#define HD 128
#define DMODEL 2048
#define BB 4
#define SQV 1024
#define SQA 64
#define SCACHE 256
#define STOT 1344   // SCACHE + SQV + SQA
#define SQTOT 1088  // SQV + SQA
#define NSPLIT 7    // attention K-partitions (192 keys = 3 chunks each)

typedef unsigned short u16;
typedef __attribute__((ext_vector_type(8))) short short8;
typedef __attribute__((ext_vector_type(4))) float f32x4;

__device__ __forceinline__ float b2f(u16 u) {
    union { float f; unsigned int i; } x; x.i = ((unsigned int)u) << 16; return x.f;
}
__device__ __forceinline__ u16 f2b(float f) {
    unsigned int x = __float_as_uint(f);
    x = x + 0x7fffu + ((x >> 16) & 1u);   // RNE
    return (u16)(x >> 16);
}

// ---------------- fused prep: RoPE tables + mask slice + KV cache ingest --------------
// grid: [0,336) tables, [336,1680) mask slice, [1680,1936) caches.
__global__ void k_prep(const float* __restrict__ mask,
                       const float* __restrict__ kc, const float* __restrict__ vc,
                       float* __restrict__ cosT, float* __restrict__ sinT,
                       u16* __restrict__ maskS, u16* __restrict__ K_all, u16* __restrict__ V_all) {
    int bx = blockIdx.x, tid = threadIdx.x;
    if (bx < 336) {
        int i = bx * 256 + tid;
        if (i < STOT * 64) {
            int p = i >> 6, j = i & 63;
            float inv = __expf(-(float)j * (9.210340371976184f / 64.0f));  // 10000^(-j/64)
            float ang = (float)p * inv;
            cosT[i] = cosf(ang);
            sinT[i] = sinf(ang);
        }
    } else if (bx < 1680) {
        int i = (bx - 336) * 256 + tid;   // 344064 = 1344*256 exact
        int b = i / (SQA * STOT);
        int r = i % (SQA * STOT);
        size_t s = (size_t)b * SQTOT * STOT + (size_t)SQV * STOT + r;
        maskS[i] = f2b(mask[s]);
    } else {
        int i = (bx - 1680) * 256 + tid;  // 65536 groups of 8
        int e = i * 8;
        int bk = e / (SCACHE * HD);
        int off = e % (SCACHE * HD);
        size_t dst = (size_t)bk * STOT * HD + off;
        const float* fk = kc + e;
        const float* fv = vc + e;
        u16 tk[8], tv[8];
#pragma unroll
        for (int j = 0; j < 8; j++) { tk[j] = f2b(fk[j]); tv[j] = f2b(fv[j]); }
        *(short8*)(K_all + dst) = *(short8*)tk;
        *(short8*)(V_all + dst) = *(short8*)tv;
    }
}

// ---------------- transpose body: fp32 [2048][N] tile -> bf16 [N][2048] ---------------
__device__ __forceinline__ void transpose_body(const float* in, u16* out, int N,
                                               int bx, int by) {
    __shared__ __align__(16) u16 t[64 * 66];
    int n0 = bx * 64, k0 = by * 64;
    int tid = threadIdx.x;
    int r = tid >> 3;
    int c8 = (tid & 7) * 8;
#pragma unroll
    for (int h = 0; h < 2; h++) {
        int k = r + h * 32;
        const float* f = in + (size_t)(k0 + k) * N + n0 + c8;
        float4 a = *(const float4*)f, b = *(const float4*)(f + 4);
        u16 vv[8] = {f2b(a.x), f2b(a.y), f2b(a.z), f2b(a.w),
                     f2b(b.x), f2b(b.y), f2b(b.z), f2b(b.w)};
#pragma unroll
        for (int j = 0; j < 8; j++) t[(c8 + j) * 66 + k] = vv[j];
    }
    __syncthreads();
#pragma unroll
    for (int h = 0; h < 2; h++) {
        int n = r + h * 32;
        short8 v;
#pragma unroll
        for (int j = 0; j < 8; j++) ((u16*)&v)[j] = t[n * 66 + c8 + j];
        *(short8*)(out + (size_t)(n0 + n) * 2048 + k0 + c8) = v;
    }
}

// all six weights in one launch: 4 small (256 blocks each) + 2 big (1024 each) = 3072
__global__ void k_transpose6(const float* w0, u16* o0, const float* w1, u16* o1,
                             const float* w2, u16* o2, const float* w3, u16* o3,
                             const float* w4, u16* o4, const float* w5, u16* o5) {
    int gx = blockIdx.x;
    if (gx < 256)        transpose_body(w0, o0, 512,  gx & 7,  gx >> 3);
    else if (gx < 512)   { int g = gx - 256;  transpose_body(w1, o1, 512,  g & 7,  g >> 3); }
    else if (gx < 768)   { int g = gx - 512;  transpose_body(w2, o2, 512,  g & 7,  g >> 3); }
    else if (gx < 1024)  { int g = gx - 768;  transpose_body(w3, o3, 512,  g & 7,  g >> 3); }
    else if (gx < 2048)  { int g = gx - 1024; transpose_body(w4, o4, 2048, g & 31, g >> 5); }
    else                 { int g = gx - 2048; transpose_body(w5, o5, 2048, g & 31, g >> 5); }
}

// ---------------- GEMM: h_vlm f32 [4096][2048] @ {WkT,WvT} bf16, fused RoPE -----------
// BM=64 BN=128 BK=64. grid (64, 8): by<4 -> K proj (kv head by), else V proj.
__global__ __launch_bounds__(256) void k_gemm_kv(
    const float* __restrict__ A, const u16* __restrict__ WkT, const u16* __restrict__ WvT,
    const int* __restrict__ pos_vlm, const float* __restrict__ cosT, const float* __restrict__ sinT,
    u16* __restrict__ K_all, u16* __restrict__ V_all) {
    __shared__ __align__(16) u16 As[64 * 72];
    __shared__ __align__(16) u16 Bs[128 * 72];
    int m0 = blockIdx.x * 64;
    int by = blockIdx.y;
    int isK = by < 4;
    const u16* Bt = isK ? WkT : WvT;
    int n0 = (by & 3) * 128;
    int tid = threadIdx.x;
    int w = tid >> 6, lane = tid & 63;
    int la = lane & 15, lg = lane >> 4;
    int wm = (w & 1) * 32;
    int c2 = w >> 1;
    int ntab[4] = {c2 * 2, c2 * 2 + 1, c2 * 2 + 4, c2 * 2 + 5};
    f32x4 acc[2][4];
#pragma unroll
    for (int i = 0; i < 2; i++)
#pragma unroll
        for (int j = 0; j < 4; j++) acc[i][j] = (f32x4){0.f, 0.f, 0.f, 0.f};
    int vrow = tid >> 3, vcol = (tid & 7) * 8;
    for (int kb = 0; kb < DMODEL; kb += 64) {
#pragma unroll
        for (int h = 0; h < 2; h++) {
            int r = vrow + h * 32;
            const float* f = A + (size_t)(m0 + r) * DMODEL + kb + vcol;
            float4 a = *(const float4*)f, b = *(const float4*)(f + 4);
            u16 vv[8] = {f2b(a.x), f2b(a.y), f2b(a.z), f2b(a.w),
                         f2b(b.x), f2b(b.y), f2b(b.z), f2b(b.w)};
            *(short8*)&As[r * 72 + vcol] = *(short8*)vv;
        }
#pragma unroll
        for (int h = 0; h < 4; h++) {
            int r = vrow + h * 32;
            *(short8*)&Bs[r * 72 + vcol] = *(const short8*)(Bt + (size_t)(n0 + r) * DMODEL + kb + vcol);
        }
        __syncthreads();
#pragma unroll
        for (int kk = 0; kk < 2; kk++) {
            short8 af[2], bf[4];
#pragma unroll
            for (int mt = 0; mt < 2; mt++) af[mt] = *(const short8*)&As[(wm + mt * 16 + la) * 72 + kk * 32 + lg * 8];
#pragma unroll
            for (int nt = 0; nt < 4; nt++) bf[nt] = *(const short8*)&Bs[(ntab[nt] * 16 + la) * 72 + kk * 32 + lg * 8];
#pragma unroll
            for (int mt = 0; mt < 2; mt++)
#pragma unroll
                for (int nt = 0; nt < 4; nt++)
                    acc[mt][nt] = __builtin_amdgcn_mfma_f32_16x16x32_bf16(af[mt], bf[nt], acc[mt][nt], 0, 0, 0);
        }
        __syncthreads();
    }
    int kv = by & 3;
#pragma unroll
    for (int mt = 0; mt < 2; mt++) {
#pragma unroll
        for (int r = 0; r < 4; r++) {
            int gm = m0 + wm + mt * 16 + lg * 4 + r;
            int b = gm >> 10, s = gm & 1023;
            size_t base = ((size_t)(b * NKV + kv) * STOT + SCACHE + s) * HD;
            if (isK) {
                int pos = pos_vlm[gm];
#pragma unroll
                for (int i = 0; i < 2; i++) {
                    int dlo = ntab[i] * 16 + la;  // in [0,64)
                    float x1 = acc[mt][i][r], x2 = acc[mt][i + 2][r];
                    float cs = cosT[pos * 64 + dlo], sn = sinT[pos * 64 + dlo];
                    K_all[base + dlo]      = f2b(x1 * cs - x2 * sn);
                    K_all[base + dlo + 64] = f2b(x2 * cs + x1 * sn);
                }
            } else {
#pragma unroll
                for (int i = 0; i < 4; i++) V_all[base + ntab[i] * 16 + la] = f2b(acc[mt][i][r]);
            }
        }
    }
}

// ---------------- GEMM: h_act f32 [256][2048] @ {Wq,Wk,Wv}_act^T bf16, fused RoPE -----
__global__ __launch_bounds__(256) void k_gemm_act(
    const float* __restrict__ A, const u16* __restrict__ WqT, const u16* __restrict__ WkT,
    const u16* __restrict__ WvT, const int* __restrict__ pos_act,
    const float* __restrict__ cosT, const float* __restrict__ sinT,
    u16* __restrict__ Qbuf, u16* __restrict__ K_all, u16* __restrict__ V_all) {
    __shared__ __align__(16) u16 As[64 * 72];
    __shared__ __align__(16) u16 Bs[128 * 72];
    int m0 = blockIdx.x * 64;
    int ny = blockIdx.y;
    const u16* Bt; int n0;
    if (ny < 16) { Bt = WqT; n0 = ny * 128; }
    else if (ny < 20) { Bt = WkT; n0 = (ny - 16) * 128; }
    else { Bt = WvT; n0 = (ny - 20) * 128; }
    int tid = threadIdx.x;
    int w = tid >> 6, lane = tid & 63;
    int la = lane & 15, lg = lane >> 4;
    int wm = (w & 1) * 32;
    int c2 = w >> 1;
    int ntab[4] = {c2 * 2, c2 * 2 + 1, c2 * 2 + 4, c2 * 2 + 5};
    f32x4 acc[2][4];
#pragma unroll
    for (int i = 0; i < 2; i++)
#pragma unroll
        for (int j = 0; j < 4; j++) acc[i][j] = (f32x4){0.f, 0.f, 0.f, 0.f};
    int vrow = tid >> 3, vcol = (tid & 7) * 8;
    for (int kb = 0; kb < DMODEL; kb += 64) {
#pragma unroll
        for (int h = 0; h < 2; h++) {
            int r = vrow + h * 32;
            const float* f = A + (size_t)(m0 + r) * DMODEL + kb + vcol;
            float4 a = *(const float4*)f, b = *(const float4*)(f + 4);
            u16 vv[8] = {f2b(a.x), f2b(a.y), f2b(a.z), f2b(a.w),
                         f2b(b.x), f2b(b.y), f2b(b.z), f2b(b.w)};
            *(short8*)&As[r * 72 + vcol] = *(short8*)vv;
        }
#pragma unroll
        for (int h = 0; h < 4; h++) {
            int r = vrow + h * 32;
            *(short8*)&Bs[r * 72 + vcol] = *(const short8*)(Bt + (size_t)(n0 + r) * DMODEL + kb + vcol);
        }
        __syncthreads();
#pragma unroll
        for (int kk = 0; kk < 2; kk++) {
            short8 af[2], bf[4];
#pragma unroll
            for (int mt = 0; mt < 2; mt++) af[mt] = *(const short8*)&As[(wm + mt * 16 + la) * 72 + kk * 32 + lg * 8];
#pragma unroll
            for (int nt = 0; nt < 4; nt++) bf[nt] = *(const short8*)&Bs[(ntab[nt] * 16 + la) * 72 + kk * 32 + lg * 8];
#pragma unroll
            for (int mt = 0; mt < 2; mt++)
#pragma unroll
                for (int nt = 0; nt < 4; nt++)
                    acc[mt][nt] = __builtin_amdgcn_mfma_f32_16x16x32_bf16(af[mt], bf[nt], acc[mt][nt], 0, 0, 0);
        }
        __syncthreads();
    }
#pragma unroll
    for (int mt = 0; mt < 2; mt++) {
#pragma unroll
        for (int r = 0; r < 4; r++) {
            int gm = m0 + wm + mt * 16 + lg * 4 + r;
            int b = gm >> 6, s = gm & 63;
            if (ny < 16) {
                int pos = pos_act[gm];
                size_t qb = ((size_t)(b * NH + ny) * SQA + s) * HD;
#pragma unroll
                for (int i = 0; i < 2; i++) {
                    int dlo = ntab[i] * 16 + la;
                    float x1 = acc[mt][i][r], x2 = acc[mt][i + 2][r];
                    float cs = cosT[pos * 64 + dlo], sn = sinT[pos * 64 + dlo];
                    Qbuf[qb + dlo]      = f2b(x1 * cs - x2 * sn);
                    Qbuf[qb + dlo + 64] = f2b(x2 * cs + x1 * sn);
                }
            } else if (ny < 20) {
                int pos = pos_act[gm];
                int kv = ny - 16;
                size_t base = ((size_t)(b * NKV + kv) * STOT + SCACHE + SQV + s) * HD;
#pragma unroll
                for (int i = 0; i < 2; i++) {
                    int dlo = ntab[i] * 16 + la;
                    float x1 = acc[mt][i][r], x2 = acc[mt][i + 2][r];
                    float cs = cosT[pos * 64 + dlo], sn = sinT[pos * 64 + dlo];
                    K_all[base + dlo]      = f2b(x1 * cs - x2 * sn);
                    K_all[base + dlo + 64] = f2b(x2 * cs + x1 * sn);
                }
            } else {
                int kv = ny - 20;
                size_t base = ((size_t)(b * NKV + kv) * STOT + SCACHE + SQV + s) * HD;
#pragma unroll
                for (int i = 0; i < 4; i++) V_all[base + ntab[i] * 16 + la] = f2b(acc[mt][i][r]);
            }
        }
    }
}

// ---------------- split-K flash attention: grid (NH, BB, NSPLIT) ----------------------
__global__ __launch_bounds__(256) void k_attn_split(
    const u16* __restrict__ Qbuf, const u16* __restrict__ K_all, const u16* __restrict__ V_all,
    const u16* __restrict__ maskS, u16* __restrict__ po, float* __restrict__ pml) {
    int h = blockIdx.x, b = blockIdx.y, p = blockIdx.z;
    int bh = b * NH + h;
    int kvh = h >> 2;
    const u16* Kb = K_all + (size_t)(b * NKV + kvh) * STOT * HD;
    const u16* Vb = V_all + (size_t)(b * NKV + kvh) * STOT * HD;
    const u16* Qb = Qbuf + (size_t)bh * SQA * HD;
    int tid = threadIdx.x, w = tid >> 6, lane = tid & 63;
    int la = lane & 15, lg = lane >> 4;
    __shared__ __align__(16) u16 Ks[64 * 136];
    __shared__ __align__(16) u16 Vs[64 * 130];
    __shared__ __align__(16) u16 Ps[4][16 * 72];
    short8 qf[4];
#pragma unroll
    for (int kk = 0; kk < 4; kk++)
        qf[kk] = *(const short8*)(Qb + (size_t)(w * 16 + la) * HD + kk * 32 + lg * 8);
    f32x4 o_acc[8];
#pragma unroll
    for (int nt = 0; nt < 8; nt++) o_acc[nt] = (f32x4){0.f, 0.f, 0.f, 0.f};
    float m_run[4], l_run[4];
#pragma unroll
    for (int r = 0; r < 4; r++) { m_run[r] = -3e38f; l_run[r] = 0.f; }
    int vr = tid >> 4;           // [0,16)
    int vc = (tid & 15) * 8;     // [0,128)
    const float scl = 0.08838834764831845f;  // 1/sqrt(128)
    for (int c = 0; c < 3; c++) {
        int g = p * 3 + c;       // global 64-key chunk
#pragma unroll
        for (int hh = 0; hh < 4; hh++) {
            int key = vr + hh * 16;
            *(short8*)&Ks[key * 136 + vc] = *(const short8*)(Kb + (size_t)(g * 64 + key) * HD + vc);
            short8 vv = *(const short8*)(Vb + (size_t)(g * 64 + key) * HD + vc);
            unsigned int* d32 = (unsigned int*)&Vs[key * 130 + vc];
#pragma unroll
            for (int q2 = 0; q2 < 4; q2++) d32[q2] = ((unsigned int*)&vv)[q2];
        }
        __syncthreads();
        f32x4 s_acc[4];
#pragma unroll
        for (int nt = 0; nt < 4; nt++) s_acc[nt] = (f32x4){0.f, 0.f, 0.f, 0.f};
#pragma unroll
        for (int kk = 0; kk < 4; kk++) {
#pragma unroll
            for (int nt = 0; nt < 4; nt++) {
                short8 kf = *(const short8*)&Ks[(nt * 16 + la) * 136 + kk * 32 + lg * 8];
                s_acc[nt] = __builtin_amdgcn_mfma_f32_16x16x32_bf16(qf[kk], kf, s_acc[nt], 0, 0, 0);
            }
        }
        float sc[4][4];
#pragma unroll
        for (int nt = 0; nt < 4; nt++) {
            int key = g * 64 + nt * 16 + la;
#pragma unroll
            for (int r = 0; r < 4; r++) {
                int sq = w * 16 + lg * 4 + r;
                float sv = s_acc[nt][r] * scl;
                sv = tanhf(sv * 0.02f) * 50.0f;
                sv += b2f(maskS[((size_t)(b * SQA + sq)) * STOT + key]);
                sc[nt][r] = sv;
            }
        }
#pragma unroll
        for (int r = 0; r < 4; r++) {
            float mx = fmaxf(fmaxf(sc[0][r], sc[1][r]), fmaxf(sc[2][r], sc[3][r]));
#pragma unroll
            for (int sh = 1; sh < 16; sh <<= 1) mx = fmaxf(mx, __shfl_xor(mx, sh, 64));
            float mn = fmaxf(m_run[r], mx);
            float alpha = __expf(m_run[r] - mn);
            m_run[r] = mn;
            float rowsum = 0.f;
#pragma unroll
            for (int nt = 0; nt < 4; nt++) {
                float pv = __expf(sc[nt][r] - mn);
                Ps[w][(lg * 4 + r) * 72 + nt * 16 + la] = f2b(pv);
                rowsum += pv;
            }
#pragma unroll
            for (int sh = 1; sh < 16; sh <<= 1) rowsum += __shfl_xor(rowsum, sh, 64);
            l_run[r] = l_run[r] * alpha + rowsum;
#pragma unroll
            for (int nt = 0; nt < 8; nt++) o_acc[nt][r] *= alpha;
        }
        __syncthreads();
#pragma unroll
        for (int kk = 0; kk < 2; kk++) {
            short8 pf = *(const short8*)&Ps[w][la * 72 + kk * 32 + lg * 8];
#pragma unroll
            for (int nt = 0; nt < 8; nt++) {
                short8 vf;
#pragma unroll
                for (int j = 0; j < 8; j++) ((u16*)&vf)[j] = Vs[(kk * 32 + lg * 8 + j) * 130 + nt * 16 + la];
                o_acc[nt] = __builtin_amdgcn_mfma_f32_16x16x32_bf16(pf, vf, o_acc[nt], 0, 0, 0);
            }
        }
        __syncthreads();
    }
#pragma unroll
    for (int nt = 0; nt < 8; nt++) {
#pragma unroll
        for (int r = 0; r < 4; r++) {
            int sq = w * 16 + lg * 4 + r;
            po[(((size_t)p * 64 + bh) * 64 + sq) * 128 + nt * 16 + la] = f2b(o_acc[nt][r]);
        }
    }
    if (la == 0) {
#pragma unroll
        for (int r = 0; r < 4; r++) {
            int sq = w * 16 + lg * 4 + r;
            size_t mlb = (((size_t)p * 64 + bh) * 64 + sq) * 2;
            pml[mlb] = m_run[r];
            pml[mlb + 1] = l_run[r];
        }
    }
}

// ---------------- attention reduce: combine NSPLIT partials -> AO bf16 ----------------
__global__ __launch_bounds__(256) void k_attn_red(
    const u16* __restrict__ po, const float* __restrict__ pml, u16* __restrict__ AO) {
    int h = blockIdx.x, b = blockIdx.y;
    int bh = b * NH + h;
    __shared__ float wgt[NSPLIT][64];
    int tid = threadIdx.x;
    if (tid < 64) {
        int q = tid;
        float m[NSPLIT], l[NSPLIT], M = -3e38f;
#pragma unroll
        for (int p = 0; p < NSPLIT; p++) {
            size_t mlb = (((size_t)p * 64 + bh) * 64 + q) * 2;
            m[p] = pml[mlb]; l[p] = pml[mlb + 1];
            M = fmaxf(M, m[p]);
        }
        float L = 0.f;
#pragma unroll
        for (int p = 0; p < NSPLIT; p++) L += l[p] * __expf(m[p] - M);
        float inv = 1.0f / L;
#pragma unroll
        for (int p = 0; p < NSPLIT; p++) wgt[p][q] = __expf(m[p] - M) * inv;
    }
    __syncthreads();
    for (int e = tid; e < 64 * 128; e += 256) {
        int q = e >> 7, d = e & 127;
        float s = 0.f;
#pragma unroll
        for (int p = 0; p < NSPLIT; p++)
            s += b2f(po[(((size_t)p * 64 + bh) * 64 + q) * 128 + d]) * wgt[p][q];
        AO[((size_t)(b * SQA + q)) * 2048 + h * HD + d] = f2b(s);
    }
}

// ---------------- final GEMM: AO[256][2048] @ WoT -> out f32. BM=64 BN=64 -------------
// grid (4, 32) = 128 WGs. Wave w: rows (w&1)*32 + {0,16}, cols (w>>1)*32 + {0,16}.
__global__ __launch_bounds__(256) void k_gemm_out(
    const u16* __restrict__ A, const u16* __restrict__ WoT, float* __restrict__ out) {
    __shared__ __align__(16) u16 As[64 * 72];
    __shared__ __align__(16) u16 Bs[64 * 72];
    int m0 = blockIdx.x * 64, n0 = blockIdx.y * 64;
    int tid = threadIdx.x;
    int w = tid >> 6, lane = tid & 63;
    int la = lane & 15, lg = lane >> 4;
    int wm = (w & 1) * 32, wn = (w >> 1) * 32;
    f32x4 acc[2][2];
#pragma unroll
    for (int i = 0; i < 2; i++)
#pragma unroll
        for (int j = 0; j < 2; j++) acc[i][j] = (f32x4){0.f, 0.f, 0.f, 0.f};
    int vrow = tid >> 3, vcol = (tid & 7) * 8;
    for (int kb = 0; kb < DMODEL; kb += 64) {
#pragma unroll
        for (int h = 0; h < 2; h++) {
            int r = vrow + h * 32;
            *(short8*)&As[r * 72 + vcol] = *(const short8*)(A + (size_t)(m0 + r) * DMODEL + kb + vcol);
            *(short8*)&Bs[r * 72 + vcol] = *(const short8*)(WoT + (size_t)(n0 + r) * DMODEL + kb + vcol);
        }
        __syncthreads();
#pragma unroll
        for (int kk = 0; kk < 2; kk++) {
            short8 af[2], bf[2];
#pragma unroll
            for (int mt = 0; mt < 2; mt++) af[mt] = *(const short8*)&As[(wm + mt * 16 + la) * 72 + kk * 32 + lg * 8];
#pragma unroll
            for (int nt = 0; nt < 2; nt++) bf[nt] = *(const short8*)&Bs[(wn + nt * 16 + la) * 72 + kk * 32 + lg * 8];
#pragma unroll
            for (int mt = 0; mt < 2; mt++)
#pragma unroll
                for (int nt = 0; nt < 2; nt++)
                    acc[mt][nt] = __builtin_amdgcn_mfma_f32_16x16x32_bf16(af[mt], bf[nt], acc[mt][nt], 0, 0, 0);
        }
        __syncthreads();
    }
#pragma unroll
    for (int mt = 0; mt < 2; mt++) {
#pragma unroll
        for (int r = 0; r < 4; r++) {
            int gm = m0 + wm + mt * 16 + lg * 4 + r;
#pragma unroll
            for (int nt = 0; nt < 2; nt++)
                out[(size_t)gm * DMODEL + n0 + wn + nt * 16 + la] = acc[mt][nt][r];
        }
    }
}

extern "C" void kernel_launch(void* const* d_in, const int* in_sizes, int n_in,
                              void* d_out, int out_size, void* d_ws, size_t ws_size,
                              hipStream_t stream) {
    (void)in_sizes; (void)n_in; (void)out_size;
    const float* mask    = (const float*)d_in[0];
    const int*   pos_vlm = (const int*)d_in[1];
    const int*   pos_act = (const int*)d_in[2];
    const float* h_vlm   = (const float*)d_in[3];
    const float* h_act   = (const float*)d_in[4];
    const float* k_cache = (const float*)d_in[5];
    const float* v_cache = (const float*)d_in[6];
    // d_in[7] = Wq_vlm -- unused (only action-query outputs are returned)
    const float* Wk_vlm  = (const float*)d_in[8];
    const float* Wv_vlm  = (const float*)d_in[9];
    const float* Wq_act  = (const float*)d_in[10];
    const float* Wk_act  = (const float*)d_in[11];
    const float* Wv_act  = (const float*)d_in[12];
    const float* Wo_act  = (const float*)d_in[13];

    // Workspace plan: 47,448,064 B (ws is 256 MiB per round-5 fill counters).
    const size_t NEED = 47448064;
    if (ws_size < NEED) return;  // diagnostic guard: finite absmax 0.215 would signal this
    char* ws = (char*)d_ws;
    float* cosT  = (float*)(ws + 0);          // 344064
    float* sinT  = (float*)(ws + 344064);     // 344064
    u16* K_all   = (u16*)(ws + 688128);       // 5505024
    u16* V_all   = (u16*)(ws + 6193152);      // 5505024
    u16* Qbuf    = (u16*)(ws + 11698176);     // 1048576
    u16* AO      = (u16*)(ws + 12746752);     // 1048576
    u16* WkvT    = (u16*)(ws + 13795328);     // 2097152
    u16* WvvT    = (u16*)(ws + 15892480);     // 2097152
    u16* WqaT    = (u16*)(ws + 17989632);     // 8388608
    u16* WkaT    = (u16*)(ws + 26378240);     // 2097152
    u16* WvaT    = (u16*)(ws + 28475392);     // 2097152
    u16* WoT     = (u16*)(ws + 30572544);     // 8388608
    u16* po      = (u16*)(ws + 38961152);     // 7340032
    float* pml   = (float*)(ws + 46301184);   // 458752
    u16* maskS   = (u16*)(ws + 46759936);     // 688128  -> end 47448064

    hipLaunchKernelGGL(k_prep, dim3(1936), dim3(256), 0, stream,
                       mask, k_cache, v_cache, cosT, sinT, maskS, K_all, V_all);
    hipLaunchKernelGGL(k_transpose6, dim3(3072), dim3(256), 0, stream,
                       Wk_vlm, WkvT, Wv_vlm, WvvT, Wk_act, WkaT, Wv_act, WvaT,
                       Wq_act, WqaT, Wo_act, WoT);
    hipLaunchKernelGGL(k_gemm_kv, dim3(64, 8), dim3(256), 0, stream,
                       h_vlm, WkvT, WvvT, pos_vlm, cosT, sinT, K_all, V_all);
    hipLaunchKernelGGL(k_gemm_act, dim3(4, 24), dim3(256), 0, stream,
                       h_act, WqaT, WkaT, WvaT, pos_act, cosT, sinT, Qbuf, K_all, V_all);
    hipLaunchKernelGGL(k_attn_split, dim3(16, 4, NSPLIT), dim3(256), 0, stream,
                       Qbuf, K_all, V_all, maskS, po, pml);
    hipLaunchKernelGGL(k_attn_red, dim3(16, 4), dim3(256), 0, stream, po, pml, AO);
    hipLaunchKernelGGL(k_gemm_out, dim3(4, 32), dim3(256), 0, stream, AO, WoT, (float*)d_out);
}

// Round 7
// 283.028 us; speedup vs baseline: 1.4421x; 1.4421x over previous
//
#include <hip/hip_runtime.h>
#include <cmath>

#define NH 16
#define NKV 4
#define HD 128
#define DMODEL 2048
#define BB 4
#define SQV 1024
#define SQA 64
#define SCACHE 256
#define STOT 1344   // SCACHE + SQV + SQA
#define SQTOT 1088  // SQV + SQA
#define NSPLIT 7    // attention K-partitions (192 keys = 3 chunks each)

typedef unsigned short u16;
typedef __attribute__((ext_vector_type(8))) short short8;
typedef __attribute__((ext_vector_type(4))) float f32x4;

__device__ __forceinline__ float b2f(u16 u) {
    union { float f; unsigned int i; } x; x.i = ((unsigned int)u) << 16; return x.f;
}
__device__ __forceinline__ u16 f2b(float f) {
    unsigned int x = __float_as_uint(f);
    x = x + 0x7fffu + ((x >> 16) & 1u);   // RNE
    return (u16)(x >> 16);
}

// ---------------- fused prep: tables + mask slice + caches + h_vlm/h_act cvt ----------
// grid: [0,336) tables, [336,1680) mask, [1680,1936) caches, [1936,6032) h_vlm,
//       [6032,6288) h_act.
__global__ void k_prep(const float* __restrict__ mask,
                       const float* __restrict__ kc, const float* __restrict__ vc,
                       const float* __restrict__ hv, const float* __restrict__ ha,
                       float* __restrict__ cosT, float* __restrict__ sinT,
                       u16* __restrict__ maskS, u16* __restrict__ K_all, u16* __restrict__ V_all,
                       u16* __restrict__ hv16, u16* __restrict__ ha16) {
    int bx = blockIdx.x, tid = threadIdx.x;
    if (bx < 336) {
        int i = bx * 256 + tid;
        if (i < STOT * 64) {
            int p = i >> 6, j = i & 63;
            float inv = __expf(-(float)j * (9.210340371976184f / 64.0f));  // 10000^(-j/64)
            float ang = (float)p * inv;
            cosT[i] = cosf(ang);
            sinT[i] = sinf(ang);
        }
    } else if (bx < 1680) {
        int i = (bx - 336) * 256 + tid;   // 344064 = 1344*256 exact
        int b = i / (SQA * STOT);
        int r = i % (SQA * STOT);
        size_t s = (size_t)b * SQTOT * STOT + (size_t)SQV * STOT + r;
        maskS[i] = f2b(mask[s]);
    } else if (bx < 1936) {
        int i = (bx - 1680) * 256 + tid;  // 65536 groups of 8
        int e = i * 8;
        int bk = e / (SCACHE * HD);
        int off = e % (SCACHE * HD);
        size_t dst = (size_t)bk * STOT * HD + off;
        const float* fk = kc + e;
        const float* fv = vc + e;
        u16 tk[8], tv[8];
#pragma unroll
        for (int j = 0; j < 8; j++) { tk[j] = f2b(fk[j]); tv[j] = f2b(fv[j]); }
        *(short8*)(K_all + dst) = *(short8*)tk;
        *(short8*)(V_all + dst) = *(short8*)tv;
    } else if (bx < 6032) {
        int i = (bx - 1936) * 256 + tid;  // 1,048,576 groups of 8
        int e = i * 8;
        const float* f = hv + e;
        float4 a = *(const float4*)f, b = *(const float4*)(f + 4);
        u16 t[8] = {f2b(a.x), f2b(a.y), f2b(a.z), f2b(a.w),
                    f2b(b.x), f2b(b.y), f2b(b.z), f2b(b.w)};
        *(short8*)(hv16 + e) = *(short8*)t;
    } else {
        int i = (bx - 6032) * 256 + tid;  // 65,536 groups of 8
        int e = i * 8;
        const float* f = ha + e;
        float4 a = *(const float4*)f, b = *(const float4*)(f + 4);
        u16 t[8] = {f2b(a.x), f2b(a.y), f2b(a.z), f2b(a.w),
                    f2b(b.x), f2b(b.y), f2b(b.z), f2b(b.w)};
        *(short8*)(ha16 + e) = *(short8*)t;
    }
}

// ---------------- transpose body: fp32 [2048][N] tile -> bf16 [N][2048] ---------------
__device__ __forceinline__ void transpose_body(const float* in, u16* out, int N,
                                               int bx, int by) {
    __shared__ __align__(16) u16 t[64 * 66];
    int n0 = bx * 64, k0 = by * 64;
    int tid = threadIdx.x;
    int r = tid >> 3;
    int c8 = (tid & 7) * 8;
#pragma unroll
    for (int h = 0; h < 2; h++) {
        int k = r + h * 32;
        const float* f = in + (size_t)(k0 + k) * N + n0 + c8;
        float4 a = *(const float4*)f, b = *(const float4*)(f + 4);
        u16 vv[8] = {f2b(a.x), f2b(a.y), f2b(a.z), f2b(a.w),
                     f2b(b.x), f2b(b.y), f2b(b.z), f2b(b.w)};
#pragma unroll
        for (int j = 0; j < 8; j++) t[(c8 + j) * 66 + k] = vv[j];
    }
    __syncthreads();
#pragma unroll
    for (int h = 0; h < 2; h++) {
        int n = r + h * 32;
        short8 v;
#pragma unroll
        for (int j = 0; j < 8; j++) ((u16*)&v)[j] = t[n * 66 + c8 + j];
        *(short8*)(out + (size_t)(n0 + n) * 2048 + k0 + c8) = v;
    }
}

// all six weights in one launch: 4 small (256 blocks each) + 2 big (1024 each) = 3072
__global__ void k_transpose6(const float* w0, u16* o0, const float* w1, u16* o1,
                             const float* w2, u16* o2, const float* w3, u16* o3,
                             const float* w4, u16* o4, const float* w5, u16* o5) {
    int gx = blockIdx.x;
    if (gx < 256)        transpose_body(w0, o0, 512,  gx & 7,  gx >> 3);
    else if (gx < 512)   { int g = gx - 256;  transpose_body(w1, o1, 512,  g & 7,  g >> 3); }
    else if (gx < 768)   { int g = gx - 512;  transpose_body(w2, o2, 512,  g & 7,  g >> 3); }
    else if (gx < 1024)  { int g = gx - 768;  transpose_body(w3, o3, 512,  g & 7,  g >> 3); }
    else if (gx < 2048)  { int g = gx - 1024; transpose_body(w4, o4, 2048, g & 31, g >> 5); }
    else                 { int g = gx - 2048; transpose_body(w5, o5, 2048, g & 31, g >> 5); }
}

// ---------------- fused QKV GEMM (round-5 verified bodies, bf16 A) --------------------
// grid (64, 10):
//   by<8:  vlm K/V proj: A=hv16[4096][2048], BM=64, by<4 -> K head by, else V head by-4.
//   by>=8: act Q/K/V proj: g=(by-8)*64+bx in [0,96): m0=(g&3)*64, ny=g>>2.
__global__ __launch_bounds__(256) void k_gemm_qkv(
    const u16* __restrict__ Avlm, const u16* __restrict__ Aact,
    const u16* __restrict__ WkvT, const u16* __restrict__ WvvT,
    const u16* __restrict__ WqaT, const u16* __restrict__ WkaT, const u16* __restrict__ WvaT,
    const int* __restrict__ pos_vlm, const int* __restrict__ pos_act,
    const float* __restrict__ cosT, const float* __restrict__ sinT,
    u16* __restrict__ Qbuf, u16* __restrict__ K_all, u16* __restrict__ V_all) {
    __shared__ __align__(16) u16 smem[64 * 72 + 128 * 72];
    u16* As = smem;
    u16* Bs = smem + 64 * 72;
    int tid = threadIdx.x;
    int w = tid >> 6, lane = tid & 63;
    int la = lane & 15, lg = lane >> 4;
    int wm = (w & 1) * 32;
    int c2 = w >> 1;
    int ntab[4] = {c2 * 2, c2 * 2 + 1, c2 * 2 + 4, c2 * 2 + 5};
    int vrow = tid >> 3, vcol = (tid & 7) * 8;

    const u16* A; const u16* Bt; int m0, n0;
    int path;                 // 0 = vlm-K, 1 = vlm-V, 2 = act-Q, 3 = act-K, 4 = act-V
    int kv_or_head = 0;
    if (blockIdx.y < 8) {
        int by = blockIdx.y;
        m0 = blockIdx.x * 64;
        A = Avlm;
        path = (by < 4) ? 0 : 1;
        kv_or_head = by & 3;
        n0 = kv_or_head * 128;
        Bt = (path == 0) ? WkvT : WvvT;
    } else {
        int g = (blockIdx.y - 8) * 64 + blockIdx.x;
        if (g >= 96) return;
        m0 = (g & 3) * 64;
        int ny = g >> 2;
        A = Aact;
        if (ny < 16)      { path = 2; kv_or_head = ny;      Bt = WqaT; n0 = ny * 128; }
        else if (ny < 20) { path = 3; kv_or_head = ny - 16; Bt = WkaT; n0 = (ny - 16) * 128; }
        else              { path = 4; kv_or_head = ny - 20; Bt = WvaT; n0 = (ny - 20) * 128; }
    }

    f32x4 acc[2][4];
#pragma unroll
    for (int i = 0; i < 2; i++)
#pragma unroll
        for (int j = 0; j < 4; j++) acc[i][j] = (f32x4){0.f, 0.f, 0.f, 0.f};
    for (int kb = 0; kb < DMODEL; kb += 64) {
#pragma unroll
        for (int h = 0; h < 2; h++) {
            int r = vrow + h * 32;
            *(short8*)&As[r * 72 + vcol] = *(const short8*)(A + (size_t)(m0 + r) * DMODEL + kb + vcol);
        }
#pragma unroll
        for (int h = 0; h < 4; h++) {
            int r = vrow + h * 32;
            *(short8*)&Bs[r * 72 + vcol] = *(const short8*)(Bt + (size_t)(n0 + r) * DMODEL + kb + vcol);
        }
        __syncthreads();
#pragma unroll
        for (int kk = 0; kk < 2; kk++) {
            short8 af[2], bf[4];
#pragma unroll
            for (int mt = 0; mt < 2; mt++) af[mt] = *(const short8*)&As[(wm + mt * 16 + la) * 72 + kk * 32 + lg * 8];
#pragma unroll
            for (int nt = 0; nt < 4; nt++) bf[nt] = *(const short8*)&Bs[(ntab[nt] * 16 + la) * 72 + kk * 32 + lg * 8];
#pragma unroll
            for (int mt = 0; mt < 2; mt++)
#pragma unroll
                for (int nt = 0; nt < 4; nt++)
                    acc[mt][nt] = __builtin_amdgcn_mfma_f32_16x16x32_bf16(af[mt], bf[nt], acc[mt][nt], 0, 0, 0);
        }
        __syncthreads();
    }

#pragma unroll
    for (int mt = 0; mt < 2; mt++) {
#pragma unroll
        for (int r = 0; r < 4; r++) {
            int gm = m0 + wm + mt * 16 + lg * 4 + r;
            if (path <= 1) {                       // vlm K/V
                int b = gm >> 10, s = gm & 1023;
                size_t base = ((size_t)(b * NKV + kv_or_head) * STOT + SCACHE + s) * HD;
                if (path == 0) {
                    int pos = pos_vlm[gm];
#pragma unroll
                    for (int i = 0; i < 2; i++) {
                        int dlo = ntab[i] * 16 + la;  // in [0,64)
                        float x1 = acc[mt][i][r], x2 = acc[mt][i + 2][r];
                        float cs = cosT[pos * 64 + dlo], sn = sinT[pos * 64 + dlo];
                        K_all[base + dlo]      = f2b(x1 * cs - x2 * sn);
                        K_all[base + dlo + 64] = f2b(x2 * cs + x1 * sn);
                    }
                } else {
#pragma unroll
                    for (int i = 0; i < 4; i++) V_all[base + ntab[i] * 16 + la] = f2b(acc[mt][i][r]);
                }
            } else {                               // action Q/K/V
                int b = gm >> 6, s = gm & 63;
                if (path == 2) {
                    int pos = pos_act[gm];
                    size_t qb = ((size_t)(b * NH + kv_or_head) * SQA + s) * HD;
#pragma unroll
                    for (int i = 0; i < 2; i++) {
                        int dlo = ntab[i] * 16 + la;
                        float x1 = acc[mt][i][r], x2 = acc[mt][i + 2][r];
                        float cs = cosT[pos * 64 + dlo], sn = sinT[pos * 64 + dlo];
                        Qbuf[qb + dlo]      = f2b(x1 * cs - x2 * sn);
                        Qbuf[qb + dlo + 64] = f2b(x2 * cs + x1 * sn);
                    }
                } else if (path == 3) {
                    int pos = pos_act[gm];
                    size_t base = ((size_t)(b * NKV + kv_or_head) * STOT + SCACHE + SQV + s) * HD;
#pragma unroll
                    for (int i = 0; i < 2; i++) {
                        int dlo = ntab[i] * 16 + la;
                        float x1 = acc[mt][i][r], x2 = acc[mt][i + 2][r];
                        float cs = cosT[pos * 64 + dlo], sn = sinT[pos * 64 + dlo];
                        K_all[base + dlo]      = f2b(x1 * cs - x2 * sn);
                        K_all[base + dlo + 64] = f2b(x2 * cs + x1 * sn);
                    }
                } else {
                    size_t base = ((size_t)(b * NKV + kv_or_head) * STOT + SCACHE + SQV + s) * HD;
#pragma unroll
                    for (int i = 0; i < 4; i++) V_all[base + ntab[i] * 16 + la] = f2b(acc[mt][i][r]);
                }
            }
        }
    }
}

// ---------------- split-K flash attention: grid (NH, BB, NSPLIT) ----------------------
__global__ __launch_bounds__(256) void k_attn_split(
    const u16* __restrict__ Qbuf, const u16* __restrict__ K_all, const u16* __restrict__ V_all,
    const u16* __restrict__ maskS, u16* __restrict__ po, float* __restrict__ pml) {
    int h = blockIdx.x, b = blockIdx.y, p = blockIdx.z;
    int bh = b * NH + h;
    int kvh = h >> 2;
    const u16* Kb = K_all + (size_t)(b * NKV + kvh) * STOT * HD;
    const u16* Vb = V_all + (size_t)(b * NKV + kvh) * STOT * HD;
    const u16* Qb = Qbuf + (size_t)bh * SQA * HD;
    int tid = threadIdx.x, w = tid >> 6, lane = tid & 63;
    int la = lane & 15, lg = lane >> 4;
    __shared__ __align__(16) u16 Ks[64 * 136];
    __shared__ __align__(16) u16 Vs[64 * 130];
    __shared__ __align__(16) u16 Ps[4][16 * 72];
    short8 qf[4];
#pragma unroll
    for (int kk = 0; kk < 4; kk++)
        qf[kk] = *(const short8*)(Qb + (size_t)(w * 16 + la) * HD + kk * 32 + lg * 8);
    f32x4 o_acc[8];
#pragma unroll
    for (int nt = 0; nt < 8; nt++) o_acc[nt] = (f32x4){0.f, 0.f, 0.f, 0.f};
    float m_run[4], l_run[4];
#pragma unroll
    for (int r = 0; r < 4; r++) { m_run[r] = -3e38f; l_run[r] = 0.f; }
    int vr = tid >> 4;           // [0,16)
    int vc = (tid & 15) * 8;     // [0,128)
    const float scl = 0.08838834764831845f;  // 1/sqrt(128)
    for (int c = 0; c < 3; c++) {
        int g = p * 3 + c;       // global 64-key chunk
#pragma unroll
        for (int hh = 0; hh < 4; hh++) {
            int key = vr + hh * 16;
            *(short8*)&Ks[key * 136 + vc] = *(const short8*)(Kb + (size_t)(g * 64 + key) * HD + vc);
            short8 vv = *(const short8*)(Vb + (size_t)(g * 64 + key) * HD + vc);
            unsigned int* d32 = (unsigned int*)&Vs[key * 130 + vc];
#pragma unroll
            for (int q2 = 0; q2 < 4; q2++) d32[q2] = ((unsigned int*)&vv)[q2];
        }
        __syncthreads();
        f32x4 s_acc[4];
#pragma unroll
        for (int nt = 0; nt < 4; nt++) s_acc[nt] = (f32x4){0.f, 0.f, 0.f, 0.f};
#pragma unroll
        for (int kk = 0; kk < 4; kk++) {
#pragma unroll
            for (int nt = 0; nt < 4; nt++) {
                short8 kf = *(const short8*)&Ks[(nt * 16 + la) * 136 + kk * 32 + lg * 8];
                s_acc[nt] = __builtin_amdgcn_mfma_f32_16x16x32_bf16(qf[kk], kf, s_acc[nt], 0, 0, 0);
            }
        }
        float sc[4][4];
#pragma unroll
        for (int nt = 0; nt < 4; nt++) {
            int key = g * 64 + nt * 16 + la;
#pragma unroll
            for (int r = 0; r < 4; r++) {
                int sq = w * 16 + lg * 4 + r;
                float sv = s_acc[nt][r] * scl;
                sv = tanhf(sv * 0.02f) * 50.0f;
                sv += b2f(maskS[((size_t)(b * SQA + sq)) * STOT + key]);
                sc[nt][r] = sv;
            }
        }
#pragma unroll
        for (int r = 0; r < 4; r++) {
            float mx = fmaxf(fmaxf(sc[0][r], sc[1][r]), fmaxf(sc[2][r], sc[3][r]));
#pragma unroll
            for (int sh = 1; sh < 16; sh <<= 1) mx = fmaxf(mx, __shfl_xor(mx, sh, 64));
            float mn = fmaxf(m_run[r], mx);
            float alpha = __expf(m_run[r] - mn);
            m_run[r] = mn;
            float rowsum = 0.f;
#pragma unroll
            for (int nt = 0; nt < 4; nt++) {
                float pv = __expf(sc[nt][r] - mn);
                Ps[w][(lg * 4 + r) * 72 + nt * 16 + la] = f2b(pv);
                rowsum += pv;
            }
#pragma unroll
            for (int sh = 1; sh < 16; sh <<= 1) rowsum += __shfl_xor(rowsum, sh, 64);
            l_run[r] = l_run[r] * alpha + rowsum;
#pragma unroll
            for (int nt = 0; nt < 8; nt++) o_acc[nt][r] *= alpha;
        }
        __syncthreads();
#pragma unroll
        for (int kk = 0; kk < 2; kk++) {
            short8 pf = *(const short8*)&Ps[w][la * 72 + kk * 32 + lg * 8];
#pragma unroll
            for (int nt = 0; nt < 8; nt++) {
                short8 vf;
#pragma unroll
                for (int j = 0; j < 8; j++) ((u16*)&vf)[j] = Vs[(kk * 32 + lg * 8 + j) * 130 + nt * 16 + la];
                o_acc[nt] = __builtin_amdgcn_mfma_f32_16x16x32_bf16(pf, vf, o_acc[nt], 0, 0, 0);
            }
        }
        __syncthreads();
    }
#pragma unroll
    for (int nt = 0; nt < 8; nt++) {
#pragma unroll
        for (int r = 0; r < 4; r++) {
            int sq = w * 16 + lg * 4 + r;
            po[(((size_t)p * 64 + bh) * 64 + sq) * 128 + nt * 16 + la] = f2b(o_acc[nt][r]);
        }
    }
    if (la == 0) {
#pragma unroll
        for (int r = 0; r < 4; r++) {
            int sq = w * 16 + lg * 4 + r;
            size_t mlb = (((size_t)p * 64 + bh) * 64 + sq) * 2;
            pml[mlb] = m_run[r];
            pml[mlb + 1] = l_run[r];
        }
    }
}

// ---------------- attention reduce: combine NSPLIT partials -> AO bf16 ----------------
__global__ __launch_bounds__(256) void k_attn_red(
    const u16* __restrict__ po, const float* __restrict__ pml, u16* __restrict__ AO) {
    int h = blockIdx.x, b = blockIdx.y;
    int bh = b * NH + h;
    __shared__ float wgt[NSPLIT][64];
    int tid = threadIdx.x;
    if (tid < 64) {
        int q = tid;
        float m[NSPLIT], l[NSPLIT], M = -3e38f;
#pragma unroll
        for (int p = 0; p < NSPLIT; p++) {
            size_t mlb = (((size_t)p * 64 + bh) * 64 + q) * 2;
            m[p] = pml[mlb]; l[p] = pml[mlb + 1];
            M = fmaxf(M, m[p]);
        }
        float L = 0.f;
#pragma unroll
        for (int p = 0; p < NSPLIT; p++) L += l[p] * __expf(m[p] - M);
        float inv = 1.0f / L;
#pragma unroll
        for (int p = 0; p < NSPLIT; p++) wgt[p][q] = __expf(m[p] - M) * inv;
    }
    __syncthreads();
    for (int e = tid; e < 64 * 128; e += 256) {
        int q = e >> 7, d = e & 127;
        float s = 0.f;
#pragma unroll
        for (int p = 0; p < NSPLIT; p++)
            s += b2f(po[(((size_t)p * 64 + bh) * 64 + q) * 128 + d]) * wgt[p][q];
        AO[((size_t)(b * SQA + q)) * 2048 + h * HD + d] = f2b(s);
    }
}

// ---------------- final GEMM: AO[256][2048] @ WoT -> out f32. BM=64 BN=64 -------------
__global__ __launch_bounds__(256) void k_gemm_out(
    const u16* __restrict__ A, const u16* __restrict__ WoT, float* __restrict__ out) {
    __shared__ __align__(16) u16 As[64 * 72];
    __shared__ __align__(16) u16 Bs[64 * 72];
    int m0 = blockIdx.x * 64, n0 = blockIdx.y * 64;
    int tid = threadIdx.x;
    int w = tid >> 6, lane = tid & 63;
    int la = lane & 15, lg = lane >> 4;
    int wm = (w & 1) * 32, wn = (w >> 1) * 32;
    f32x4 acc[2][2];
#pragma unroll
    for (int i = 0; i < 2; i++)
#pragma unroll
        for (int j = 0; j < 2; j++) acc[i][j] = (f32x4){0.f, 0.f, 0.f, 0.f};
    int vrow = tid >> 3, vcol = (tid & 7) * 8;
    for (int kb = 0; kb < DMODEL; kb += 64) {
#pragma unroll
        for (int h = 0; h < 2; h++) {
            int r = vrow + h * 32;
            *(short8*)&As[r * 72 + vcol] = *(const short8*)(A + (size_t)(m0 + r) * DMODEL + kb + vcol);
            *(short8*)&Bs[r * 72 + vcol] = *(const short8*)(WoT + (size_t)(n0 + r) * DMODEL + kb + vcol);
        }
        __syncthreads();
#pragma unroll
        for (int kk = 0; kk < 2; kk++) {
            short8 af[2], bf[2];
#pragma unroll
            for (int mt = 0; mt < 2; mt++) af[mt] = *(const short8*)&As[(wm + mt * 16 + la) * 72 + kk * 32 + lg * 8];
#pragma unroll
            for (int nt = 0; nt < 2; nt++) bf[nt] = *(const short8*)&Bs[(wn + nt * 16 + la) * 72 + kk * 32 + lg * 8];
#pragma unroll
            for (int mt = 0; mt < 2; mt++)
#pragma unroll
                for (int nt = 0; nt < 2; nt++)
                    acc[mt][nt] = __builtin_amdgcn_mfma_f32_16x16x32_bf16(af[mt], bf[nt], acc[mt][nt], 0, 0, 0);
        }
        __syncthreads();
    }
#pragma unroll
    for (int mt = 0; mt < 2; mt++) {
#pragma unroll
        for (int r = 0; r < 4; r++) {
            int gm = m0 + wm + mt * 16 + lg * 4 + r;
#pragma unroll
            for (int nt = 0; nt < 2; nt++)
                out[(size_t)gm * DMODEL + n0 + wn + nt * 16 + la] = acc[mt][nt][r];
        }
    }
}

extern "C" void kernel_launch(void* const* d_in, const int* in_sizes, int n_in,
                              void* d_out, int out_size, void* d_ws, size_t ws_size,
                              hipStream_t stream) {
    (void)in_sizes; (void)n_in; (void)out_size;
    const float* mask    = (const float*)d_in[0];
    const int*   pos_vlm = (const int*)d_in[1];
    const int*   pos_act = (const int*)d_in[2];
    const float* h_vlm   = (const float*)d_in[3];
    const float* h_act   = (const float*)d_in[4];
    const float* k_cache = (const float*)d_in[5];
    const float* v_cache = (const float*)d_in[6];
    // d_in[7] = Wq_vlm -- unused (only action-query outputs are returned)
    const float* Wk_vlm  = (const float*)d_in[8];
    const float* Wv_vlm  = (const float*)d_in[9];
    const float* Wq_act  = (const float*)d_in[10];
    const float* Wk_act  = (const float*)d_in[11];
    const float* Wv_act  = (const float*)d_in[12];
    const float* Wo_act  = (const float*)d_in[13];

    // Workspace plan: 65,273,856 B (d_ws is 256 MiB per round-5 fill counters).
    const size_t NEED = 65273856;
    if (ws_size < NEED) return;
    char* ws = (char*)d_ws;
    float* cosT  = (float*)(ws + 0);          // 344064
    float* sinT  = (float*)(ws + 344064);     // 344064
    u16* K_all   = (u16*)(ws + 688128);       // 5505024
    u16* V_all   = (u16*)(ws + 6193152);      // 5505024
    u16* Qbuf    = (u16*)(ws + 11698176);     // 1048576
    u16* AO      = (u16*)(ws + 12746752);     // 1048576
    u16* WkvT    = (u16*)(ws + 13795328);     // 2097152
    u16* WvvT    = (u16*)(ws + 15892480);     // 2097152
    u16* WqaT    = (u16*)(ws + 17989632);     // 8388608
    u16* WkaT    = (u16*)(ws + 26378240);     // 2097152
    u16* WvaT    = (u16*)(ws + 28475392);     // 2097152
    u16* WoT     = (u16*)(ws + 30572544);     // 8388608
    u16* po      = (u16*)(ws + 38961152);     // 7340032
    float* pml   = (float*)(ws + 46301184);   // 458752
    u16* maskS   = (u16*)(ws + 46759936);     // 688128
    u16* hv16    = (u16*)(ws + 47448064);     // 16777216
    u16* ha16    = (u16*)(ws + 64225280);     // 1048576  -> end 65273856

    hipLaunchKernelGGL(k_prep, dim3(6288), dim3(256), 0, stream,
                       mask, k_cache, v_cache, h_vlm, h_act,
                       cosT, sinT, maskS, K_all, V_all, hv16, ha16);
    hipLaunchKernelGGL(k_transpose6, dim3(3072), dim3(256), 0, stream,
                       Wk_vlm, WkvT, Wv_vlm, WvvT, Wk_act, WkaT, Wv_act, WvaT,
                       Wq_act, WqaT, Wo_act, WoT);
    hipLaunchKernelGGL(k_gemm_qkv, dim3(64, 10), dim3(256), 0, stream,
                       hv16, ha16, WkvT, WvvT, WqaT, WkaT, WvaT,
                       pos_vlm, pos_act, cosT, sinT, Qbuf, K_all, V_all);
    hipLaunchKernelGGL(k_attn_split, dim3(16, 4, NSPLIT), dim3(256), 0, stream,
                       Qbuf, K_all, V_all, maskS, po, pml);
    hipLaunchKernelGGL(k_attn_red, dim3(16, 4), dim3(256), 0, stream, po, pml, AO);
    hipLaunchKernelGGL(k_gemm_out, dim3(4, 32), dim3(256), 0, stream, AO, WoT, (float*)d_out);
}

// Round 8
// 253.650 us; speedup vs baseline: 1.6092x; 1.1158x over previous
//
#include <hip/hip_runtime.h>
#include <cmath>

#define NH 16
#define NKV 4
#define HD 128
#define DMODEL 2048
#define BB 4
#define SQV 1024
#define SQA 64
#define SCACHE 256
#define STOT 1344   // SCACHE + SQV + SQA
#define SQTOT 1088  // SQV + SQA
#define NSPLIT 7    // attention K-partitions (192 keys = 3 chunks each)

typedef unsigned short u16;
typedef __attribute__((ext_vector_type(8))) short short8;
typedef __attribute__((ext_vector_type(4))) float f32x4;

__device__ __forceinline__ float b2f(u16 u) {
    union { float f; unsigned int i; } x; x.i = ((unsigned int)u) << 16; return x.f;
}
__device__ __forceinline__ u16 f2b(float f) {
    unsigned int x = __float_as_uint(f);
    x = x + 0x7fffu + ((x >> 16) & 1u);   // RNE
    return (u16)(x >> 16);
}

// ---------------- fused prep: tables + mask slice + caches + h_vlm/h_act cvt ----------
__global__ void k_prep(const float* __restrict__ mask,
                       const float* __restrict__ kc, const float* __restrict__ vc,
                       const float* __restrict__ hv, const float* __restrict__ ha,
                       float* __restrict__ cosT, float* __restrict__ sinT,
                       u16* __restrict__ maskS, u16* __restrict__ K_all, u16* __restrict__ V_all,
                       u16* __restrict__ hv16, u16* __restrict__ ha16) {
    int bx = blockIdx.x, tid = threadIdx.x;
    if (bx < 336) {
        int i = bx * 256 + tid;
        if (i < STOT * 64) {
            int p = i >> 6, j = i & 63;
            float inv = __expf(-(float)j * (9.210340371976184f / 64.0f));  // 10000^(-j/64)
            float ang = (float)p * inv;
            cosT[i] = cosf(ang);
            sinT[i] = sinf(ang);
        }
    } else if (bx < 1680) {
        int i = (bx - 336) * 256 + tid;   // 344064 = 1344*256 exact
        int b = i / (SQA * STOT);
        int r = i % (SQA * STOT);
        size_t s = (size_t)b * SQTOT * STOT + (size_t)SQV * STOT + r;
        maskS[i] = f2b(mask[s]);
    } else if (bx < 1936) {
        int i = (bx - 1680) * 256 + tid;  // 65536 groups of 8
        int e = i * 8;
        int bk = e / (SCACHE * HD);
        int off = e % (SCACHE * HD);
        size_t dst = (size_t)bk * STOT * HD + off;
        const float* fk = kc + e;
        const float* fv = vc + e;
        u16 tk[8], tv[8];
#pragma unroll
        for (int j = 0; j < 8; j++) { tk[j] = f2b(fk[j]); tv[j] = f2b(fv[j]); }
        *(short8*)(K_all + dst) = *(short8*)tk;
        *(short8*)(V_all + dst) = *(short8*)tv;
    } else if (bx < 6032) {
        int i = (bx - 1936) * 256 + tid;  // 1,048,576 groups of 8
        int e = i * 8;
        const float* f = hv + e;
        float4 a = *(const float4*)f, b = *(const float4*)(f + 4);
        u16 t[8] = {f2b(a.x), f2b(a.y), f2b(a.z), f2b(a.w),
                    f2b(b.x), f2b(b.y), f2b(b.z), f2b(b.w)};
        *(short8*)(hv16 + e) = *(short8*)t;
    } else {
        int i = (bx - 6032) * 256 + tid;  // 65,536 groups of 8
        int e = i * 8;
        const float* f = ha + e;
        float4 a = *(const float4*)f, b = *(const float4*)(f + 4);
        u16 t[8] = {f2b(a.x), f2b(a.y), f2b(a.z), f2b(a.w),
                    f2b(b.x), f2b(b.y), f2b(b.z), f2b(b.w)};
        *(short8*)(ha16 + e) = *(short8*)t;
    }
}

// ---------------- transpose body: fp32 [2048][N] tile -> bf16 [N][2048] ---------------
__device__ __forceinline__ void transpose_body(const float* in, u16* out, int N,
                                               int bx, int by) {
    __shared__ __align__(16) u16 t[64 * 66];
    int n0 = bx * 64, k0 = by * 64;
    int tid = threadIdx.x;
    int r = tid >> 3;
    int c8 = (tid & 7) * 8;
#pragma unroll
    for (int h = 0; h < 2; h++) {
        int k = r + h * 32;
        const float* f = in + (size_t)(k0 + k) * N + n0 + c8;
        float4 a = *(const float4*)f, b = *(const float4*)(f + 4);
        u16 vv[8] = {f2b(a.x), f2b(a.y), f2b(a.z), f2b(a.w),
                     f2b(b.x), f2b(b.y), f2b(b.z), f2b(b.w)};
#pragma unroll
        for (int j = 0; j < 8; j++) t[(c8 + j) * 66 + k] = vv[j];
    }
    __syncthreads();
#pragma unroll
    for (int h = 0; h < 2; h++) {
        int n = r + h * 32;
        short8 v;
#pragma unroll
        for (int j = 0; j < 8; j++) ((u16*)&v)[j] = t[n * 66 + c8 + j];
        *(short8*)(out + (size_t)(n0 + n) * 2048 + k0 + c8) = v;
    }
}

__global__ void k_transpose6(const float* w0, u16* o0, const float* w1, u16* o1,
                             const float* w2, u16* o2, const float* w3, u16* o3,
                             const float* w4, u16* o4, const float* w5, u16* o5) {
    int gx = blockIdx.x;
    if (gx < 256)        transpose_body(w0, o0, 512,  gx & 7,  gx >> 3);
    else if (gx < 512)   { int g = gx - 256;  transpose_body(w1, o1, 512,  g & 7,  g >> 3); }
    else if (gx < 768)   { int g = gx - 512;  transpose_body(w2, o2, 512,  g & 7,  g >> 3); }
    else if (gx < 1024)  { int g = gx - 768;  transpose_body(w3, o3, 512,  g & 7,  g >> 3); }
    else if (gx < 2048)  { int g = gx - 1024; transpose_body(w4, o4, 2048, g & 31, g >> 5); }
    else                 { int g = gx - 2048; transpose_body(w5, o5, 2048, g & 31, g >> 5); }
}

// ---------------- fused QKV GEMM with register-prefetch pipeline ----------------------
// grid (64, 10):
//   by<8:  vlm K/V proj: A=hv16[4096][2048], BM=64, by<4 -> K head by, else V head by-4.
//   by>=8: act Q/K/V proj: g=(by-8)*64+bx in [0,96): m0=(g&3)*64, ny=g>>2.
// K-loop pipelining: kb+1's A/B fragments are global-loaded into VGPRs right after the
// first barrier, overlapping the ~900-cyc HBM latency with the ds_read+MFMA phase.
__global__ __launch_bounds__(256) void k_gemm_qkv(
    const u16* __restrict__ Avlm, const u16* __restrict__ Aact,
    const u16* __restrict__ WkvT, const u16* __restrict__ WvvT,
    const u16* __restrict__ WqaT, const u16* __restrict__ WkaT, const u16* __restrict__ WvaT,
    const int* __restrict__ pos_vlm, const int* __restrict__ pos_act,
    const float* __restrict__ cosT, const float* __restrict__ sinT,
    u16* __restrict__ Qbuf, u16* __restrict__ K_all, u16* __restrict__ V_all) {
    __shared__ __align__(16) u16 smem[64 * 72 + 128 * 72];
    u16* As = smem;
    u16* Bs = smem + 64 * 72;
    int tid = threadIdx.x;
    int w = tid >> 6, lane = tid & 63;
    int la = lane & 15, lg = lane >> 4;
    int wm = (w & 1) * 32;
    int c2 = w >> 1;
    int ntab[4] = {c2 * 2, c2 * 2 + 1, c2 * 2 + 4, c2 * 2 + 5};
    int vrow = tid >> 3, vcol = (tid & 7) * 8;

    const u16* A; const u16* Bt; int m0, n0;
    int path;                 // 0 = vlm-K, 1 = vlm-V, 2 = act-Q, 3 = act-K, 4 = act-V
    int kv_or_head = 0;
    if (blockIdx.y < 8) {
        int by = blockIdx.y;
        m0 = blockIdx.x * 64;
        A = Avlm;
        path = (by < 4) ? 0 : 1;
        kv_or_head = by & 3;
        n0 = kv_or_head * 128;
        Bt = (path == 0) ? WkvT : WvvT;
    } else {
        int g = (blockIdx.y - 8) * 64 + blockIdx.x;
        if (g >= 96) return;
        m0 = (g & 3) * 64;
        int ny = g >> 2;
        A = Aact;
        if (ny < 16)      { path = 2; kv_or_head = ny;      Bt = WqaT; n0 = ny * 128; }
        else if (ny < 20) { path = 3; kv_or_head = ny - 16; Bt = WkaT; n0 = (ny - 16) * 128; }
        else              { path = 4; kv_or_head = ny - 20; Bt = WvaT; n0 = (ny - 20) * 128; }
    }

    f32x4 acc[2][4];
#pragma unroll
    for (int i = 0; i < 2; i++)
#pragma unroll
        for (int j = 0; j < 4; j++) acc[i][j] = (f32x4){0.f, 0.f, 0.f, 0.f};

    short8 pa[2], pb[4];
#pragma unroll
    for (int h = 0; h < 2; h++)
        pa[h] = *(const short8*)(A + (size_t)(m0 + vrow + h * 32) * DMODEL + vcol);
#pragma unroll
    for (int h = 0; h < 4; h++)
        pb[h] = *(const short8*)(Bt + (size_t)(n0 + vrow + h * 32) * DMODEL + vcol);

    for (int kb = 0; kb < DMODEL; kb += 64) {
#pragma unroll
        for (int h = 0; h < 2; h++)
            *(short8*)&As[(vrow + h * 32) * 72 + vcol] = pa[h];
#pragma unroll
        for (int h = 0; h < 4; h++)
            *(short8*)&Bs[(vrow + h * 32) * 72 + vcol] = pb[h];
        __syncthreads();
        // prefetch next K-tile (clamped re-load of last tile: branchless, harmless)
        int kn = (kb + 64 < DMODEL) ? kb + 64 : kb;
#pragma unroll
        for (int h = 0; h < 2; h++)
            pa[h] = *(const short8*)(A + (size_t)(m0 + vrow + h * 32) * DMODEL + kn + vcol);
#pragma unroll
        for (int h = 0; h < 4; h++)
            pb[h] = *(const short8*)(Bt + (size_t)(n0 + vrow + h * 32) * DMODEL + kn + vcol);
#pragma unroll
        for (int kk = 0; kk < 2; kk++) {
            short8 af[2], bf[4];
#pragma unroll
            for (int mt = 0; mt < 2; mt++) af[mt] = *(const short8*)&As[(wm + mt * 16 + la) * 72 + kk * 32 + lg * 8];
#pragma unroll
            for (int nt = 0; nt < 4; nt++) bf[nt] = *(const short8*)&Bs[(ntab[nt] * 16 + la) * 72 + kk * 32 + lg * 8];
#pragma unroll
            for (int mt = 0; mt < 2; mt++)
#pragma unroll
                for (int nt = 0; nt < 4; nt++)
                    acc[mt][nt] = __builtin_amdgcn_mfma_f32_16x16x32_bf16(af[mt], bf[nt], acc[mt][nt], 0, 0, 0);
        }
        __syncthreads();
    }

#pragma unroll
    for (int mt = 0; mt < 2; mt++) {
#pragma unroll
        for (int r = 0; r < 4; r++) {
            int gm = m0 + wm + mt * 16 + lg * 4 + r;
            if (path <= 1) {                       // vlm K/V
                int b = gm >> 10, s = gm & 1023;
                size_t base = ((size_t)(b * NKV + kv_or_head) * STOT + SCACHE + s) * HD;
                if (path == 0) {
                    int pos = pos_vlm[gm];
#pragma unroll
                    for (int i = 0; i < 2; i++) {
                        int dlo = ntab[i] * 16 + la;  // in [0,64)
                        float x1 = acc[mt][i][r], x2 = acc[mt][i + 2][r];
                        float cs = cosT[pos * 64 + dlo], sn = sinT[pos * 64 + dlo];
                        K_all[base + dlo]      = f2b(x1 * cs - x2 * sn);
                        K_all[base + dlo + 64] = f2b(x2 * cs + x1 * sn);
                    }
                } else {
#pragma unroll
                    for (int i = 0; i < 4; i++) V_all[base + ntab[i] * 16 + la] = f2b(acc[mt][i][r]);
                }
            } else {                               // action Q/K/V
                int b = gm >> 6, s = gm & 63;
                if (path == 2) {
                    int pos = pos_act[gm];
                    size_t qb = ((size_t)(b * NH + kv_or_head) * SQA + s) * HD;
#pragma unroll
                    for (int i = 0; i < 2; i++) {
                        int dlo = ntab[i] * 16 + la;
                        float x1 = acc[mt][i][r], x2 = acc[mt][i + 2][r];
                        float cs = cosT[pos * 64 + dlo], sn = sinT[pos * 64 + dlo];
                        Qbuf[qb + dlo]      = f2b(x1 * cs - x2 * sn);
                        Qbuf[qb + dlo + 64] = f2b(x2 * cs + x1 * sn);
                    }
                } else if (path == 3) {
                    int pos = pos_act[gm];
                    size_t base = ((size_t)(b * NKV + kv_or_head) * STOT + SCACHE + SQV + s) * HD;
#pragma unroll
                    for (int i = 0; i < 2; i++) {
                        int dlo = ntab[i] * 16 + la;
                        float x1 = acc[mt][i][r], x2 = acc[mt][i + 2][r];
                        float cs = cosT[pos * 64 + dlo], sn = sinT[pos * 64 + dlo];
                        K_all[base + dlo]      = f2b(x1 * cs - x2 * sn);
                        K_all[base + dlo + 64] = f2b(x2 * cs + x1 * sn);
                    }
                } else {
                    size_t base = ((size_t)(b * NKV + kv_or_head) * STOT + SCACHE + SQV + s) * HD;
#pragma unroll
                    for (int i = 0; i < 4; i++) V_all[base + ntab[i] * 16 + la] = f2b(acc[mt][i][r]);
                }
            }
        }
    }
}

// ---------------- split-K flash attention: grid (NH, BB, NSPLIT) ----------------------
__global__ __launch_bounds__(256) void k_attn_split(
    const u16* __restrict__ Qbuf, const u16* __restrict__ K_all, const u16* __restrict__ V_all,
    const u16* __restrict__ maskS, u16* __restrict__ po, float* __restrict__ pml) {
    int h = blockIdx.x, b = blockIdx.y, p = blockIdx.z;
    int bh = b * NH + h;
    int kvh = h >> 2;
    const u16* Kb = K_all + (size_t)(b * NKV + kvh) * STOT * HD;
    const u16* Vb = V_all + (size_t)(b * NKV + kvh) * STOT * HD;
    const u16* Qb = Qbuf + (size_t)bh * SQA * HD;
    int tid = threadIdx.x, w = tid >> 6, lane = tid & 63;
    int la = lane & 15, lg = lane >> 4;
    __shared__ __align__(16) u16 Ks[64 * 136];
    __shared__ __align__(16) u16 Vs[64 * 130];
    __shared__ __align__(16) u16 Ps[4][16 * 72];
    short8 qf[4];
#pragma unroll
    for (int kk = 0; kk < 4; kk++)
        qf[kk] = *(const short8*)(Qb + (size_t)(w * 16 + la) * HD + kk * 32 + lg * 8);
    f32x4 o_acc[8];
#pragma unroll
    for (int nt = 0; nt < 8; nt++) o_acc[nt] = (f32x4){0.f, 0.f, 0.f, 0.f};
    float m_run[4], l_run[4];
#pragma unroll
    for (int r = 0; r < 4; r++) { m_run[r] = -3e38f; l_run[r] = 0.f; }
    int vr = tid >> 4;           // [0,16)
    int vc = (tid & 15) * 8;     // [0,128)
    const float scl = 0.08838834764831845f;  // 1/sqrt(128)
    for (int c = 0; c < 3; c++) {
        int g = p * 3 + c;       // global 64-key chunk
#pragma unroll
        for (int hh = 0; hh < 4; hh++) {
            int key = vr + hh * 16;
            *(short8*)&Ks[key * 136 + vc] = *(const short8*)(Kb + (size_t)(g * 64 + key) * HD + vc);
            short8 vv = *(const short8*)(Vb + (size_t)(g * 64 + key) * HD + vc);
            unsigned int* d32 = (unsigned int*)&Vs[key * 130 + vc];
#pragma unroll
            for (int q2 = 0; q2 < 4; q2++) d32[q2] = ((unsigned int*)&vv)[q2];
        }
        __syncthreads();
        f32x4 s_acc[4];
#pragma unroll
        for (int nt = 0; nt < 4; nt++) s_acc[nt] = (f32x4){0.f, 0.f, 0.f, 0.f};
#pragma unroll
        for (int kk = 0; kk < 4; kk++) {
#pragma unroll
            for (int nt = 0; nt < 4; nt++) {
                short8 kf = *(const short8*)&Ks[(nt * 16 + la) * 136 + kk * 32 + lg * 8];
                s_acc[nt] = __builtin_amdgcn_mfma_f32_16x16x32_bf16(qf[kk], kf, s_acc[nt], 0, 0, 0);
            }
        }
        float sc[4][4];
#pragma unroll
        for (int nt = 0; nt < 4; nt++) {
            int key = g * 64 + nt * 16 + la;
#pragma unroll
            for (int r = 0; r < 4; r++) {
                int sq = w * 16 + lg * 4 + r;
                float sv = s_acc[nt][r] * scl;
                sv = tanhf(sv * 0.02f) * 50.0f;
                sv += b2f(maskS[((size_t)(b * SQA + sq)) * STOT + key]);
                sc[nt][r] = sv;
            }
        }
#pragma unroll
        for (int r = 0; r < 4; r++) {
            float mx = fmaxf(fmaxf(sc[0][r], sc[1][r]), fmaxf(sc[2][r], sc[3][r]));
#pragma unroll
            for (int sh = 1; sh < 16; sh <<= 1) mx = fmaxf(mx, __shfl_xor(mx, sh, 64));
            float mn = fmaxf(m_run[r], mx);
            float alpha = __expf(m_run[r] - mn);
            m_run[r] = mn;
            float rowsum = 0.f;
#pragma unroll
            for (int nt = 0; nt < 4; nt++) {
                float pv = __expf(sc[nt][r] - mn);
                Ps[w][(lg * 4 + r) * 72 + nt * 16 + la] = f2b(pv);
                rowsum += pv;
            }
#pragma unroll
            for (int sh = 1; sh < 16; sh <<= 1) rowsum += __shfl_xor(rowsum, sh, 64);
            l_run[r] = l_run[r] * alpha + rowsum;
#pragma unroll
            for (int nt = 0; nt < 8; nt++) o_acc[nt][r] *= alpha;
        }
        __syncthreads();
#pragma unroll
        for (int kk = 0; kk < 2; kk++) {
            short8 pf = *(const short8*)&Ps[w][la * 72 + kk * 32 + lg * 8];
#pragma unroll
            for (int nt = 0; nt < 8; nt++) {
                short8 vf;
#pragma unroll
                for (int j = 0; j < 8; j++) ((u16*)&vf)[j] = Vs[(kk * 32 + lg * 8 + j) * 130 + nt * 16 + la];
                o_acc[nt] = __builtin_amdgcn_mfma_f32_16x16x32_bf16(pf, vf, o_acc[nt], 0, 0, 0);
            }
        }
        __syncthreads();
    }
#pragma unroll
    for (int nt = 0; nt < 8; nt++) {
#pragma unroll
        for (int r = 0; r < 4; r++) {
            int sq = w * 16 + lg * 4 + r;
            po[(((size_t)p * 64 + bh) * 64 + sq) * 128 + nt * 16 + la] = f2b(o_acc[nt][r]);
        }
    }
    if (la == 0) {
#pragma unroll
        for (int r = 0; r < 4; r++) {
            int sq = w * 16 + lg * 4 + r;
            size_t mlb = (((size_t)p * 64 + bh) * 64 + sq) * 2;
            pml[mlb] = m_run[r];
            pml[mlb + 1] = l_run[r];
        }
    }
}

// ---------------- attention reduce: combine NSPLIT partials -> AO bf16 ----------------
__global__ __launch_bounds__(256) void k_attn_red(
    const u16* __restrict__ po, const float* __restrict__ pml, u16* __restrict__ AO) {
    int h = blockIdx.x, b = blockIdx.y;
    int bh = b * NH + h;
    __shared__ float wgt[NSPLIT][64];
    int tid = threadIdx.x;
    if (tid < 64) {
        int q = tid;
        float m[NSPLIT], l[NSPLIT], M = -3e38f;
#pragma unroll
        for (int p = 0; p < NSPLIT; p++) {
            size_t mlb = (((size_t)p * 64 + bh) * 64 + q) * 2;
            m[p] = pml[mlb]; l[p] = pml[mlb + 1];
            M = fmaxf(M, m[p]);
        }
        float L = 0.f;
#pragma unroll
        for (int p = 0; p < NSPLIT; p++) L += l[p] * __expf(m[p] - M);
        float inv = 1.0f / L;
#pragma unroll
        for (int p = 0; p < NSPLIT; p++) wgt[p][q] = __expf(m[p] - M) * inv;
    }
    __syncthreads();
    for (int e = tid; e < 64 * 128; e += 256) {
        int q = e >> 7, d = e & 127;
        float s = 0.f;
#pragma unroll
        for (int p = 0; p < NSPLIT; p++)
            s += b2f(po[(((size_t)p * 64 + bh) * 64 + q) * 128 + d]) * wgt[p][q];
        AO[((size_t)(b * SQA + q)) * 2048 + h * HD + d] = f2b(s);
    }
}

// ---------------- final GEMM: AO[256][2048] @ WoT -> out f32, prefetch-pipelined ------
__global__ __launch_bounds__(256) void k_gemm_out(
    const u16* __restrict__ A, const u16* __restrict__ WoT, float* __restrict__ out) {
    __shared__ __align__(16) u16 As[64 * 72];
    __shared__ __align__(16) u16 Bs[64 * 72];
    int m0 = blockIdx.x * 64, n0 = blockIdx.y * 64;
    int tid = threadIdx.x;
    int w = tid >> 6, lane = tid & 63;
    int la = lane & 15, lg = lane >> 4;
    int wm = (w & 1) * 32, wn = (w >> 1) * 32;
    f32x4 acc[2][2];
#pragma unroll
    for (int i = 0; i < 2; i++)
#pragma unroll
        for (int j = 0; j < 2; j++) acc[i][j] = (f32x4){0.f, 0.f, 0.f, 0.f};
    int vrow = tid >> 3, vcol = (tid & 7) * 8;
    short8 pa[2], pb[2];
#pragma unroll
    for (int h = 0; h < 2; h++) {
        pa[h] = *(const short8*)(A   + (size_t)(m0 + vrow + h * 32) * DMODEL + vcol);
        pb[h] = *(const short8*)(WoT + (size_t)(n0 + vrow + h * 32) * DMODEL + vcol);
    }
    for (int kb = 0; kb < DMODEL; kb += 64) {
#pragma unroll
        for (int h = 0; h < 2; h++) {
            *(short8*)&As[(vrow + h * 32) * 72 + vcol] = pa[h];
            *(short8*)&Bs[(vrow + h * 32) * 72 + vcol] = pb[h];
        }
        __syncthreads();
        int kn = (kb + 64 < DMODEL) ? kb + 64 : kb;
#pragma unroll
        for (int h = 0; h < 2; h++) {
            pa[h] = *(const short8*)(A   + (size_t)(m0 + vrow + h * 32) * DMODEL + kn + vcol);
            pb[h] = *(const short8*)(WoT + (size_t)(n0 + vrow + h * 32) * DMODEL + kn + vcol);
        }
#pragma unroll
        for (int kk = 0; kk < 2; kk++) {
            short8 af[2], bf[2];
#pragma unroll
            for (int mt = 0; mt < 2; mt++) af[mt] = *(const short8*)&As[(wm + mt * 16 + la) * 72 + kk * 32 + lg * 8];
#pragma unroll
            for (int nt = 0; nt < 2; nt++) bf[nt] = *(const short8*)&Bs[(wn + nt * 16 + la) * 72 + kk * 32 + lg * 8];
#pragma unroll
            for (int mt = 0; mt < 2; mt++)
#pragma unroll
                for (int nt = 0; nt < 2; nt++)
                    acc[mt][nt] = __builtin_amdgcn_mfma_f32_16x16x32_bf16(af[mt], bf[nt], acc[mt][nt], 0, 0, 0);
        }
        __syncthreads();
    }
#pragma unroll
    for (int mt = 0; mt < 2; mt++) {
#pragma unroll
        for (int r = 0; r < 4; r++) {
            int gm = m0 + wm + mt * 16 + lg * 4 + r;
#pragma unroll
            for (int nt = 0; nt < 2; nt++)
                out[(size_t)gm * DMODEL + n0 + wn + nt * 16 + la] = acc[mt][nt][r];
        }
    }
}

extern "C" void kernel_launch(void* const* d_in, const int* in_sizes, int n_in,
                              void* d_out, int out_size, void* d_ws, size_t ws_size,
                              hipStream_t stream) {
    (void)in_sizes; (void)n_in; (void)out_size;
    const float* mask    = (const float*)d_in[0];
    const int*   pos_vlm = (const int*)d_in[1];
    const int*   pos_act = (const int*)d_in[2];
    const float* h_vlm   = (const float*)d_in[3];
    const float* h_act   = (const float*)d_in[4];
    const float* k_cache = (const float*)d_in[5];
    const float* v_cache = (const float*)d_in[6];
    // d_in[7] = Wq_vlm -- unused (only action-query outputs are returned)
    const float* Wk_vlm  = (const float*)d_in[8];
    const float* Wv_vlm  = (const float*)d_in[9];
    const float* Wq_act  = (const float*)d_in[10];
    const float* Wk_act  = (const float*)d_in[11];
    const float* Wv_act  = (const float*)d_in[12];
    const float* Wo_act  = (const float*)d_in[13];

    // Workspace plan: 65,273,856 B (d_ws is 256 MiB per round-5 fill counters).
    const size_t NEED = 65273856;
    if (ws_size < NEED) return;
    char* ws = (char*)d_ws;
    float* cosT  = (float*)(ws + 0);          // 344064
    float* sinT  = (float*)(ws + 344064);     // 344064
    u16* K_all   = (u16*)(ws + 688128);       // 5505024
    u16* V_all   = (u16*)(ws + 6193152);      // 5505024
    u16* Qbuf    = (u16*)(ws + 11698176);     // 1048576
    u16* AO      = (u16*)(ws + 12746752);     // 1048576
    u16* WkvT    = (u16*)(ws + 13795328);     // 2097152
    u16* WvvT    = (u16*)(ws + 15892480);     // 2097152
    u16* WqaT    = (u16*)(ws + 17989632);     // 8388608
    u16* WkaT    = (u16*)(ws + 26378240);     // 2097152
    u16* WvaT    = (u16*)(ws + 28475392);     // 2097152
    u16* WoT     = (u16*)(ws + 30572544);     // 8388608
    u16* po      = (u16*)(ws + 38961152);     // 7340032
    float* pml   = (float*)(ws + 46301184);   // 458752
    u16* maskS   = (u16*)(ws + 46759936);     // 688128
    u16* hv16    = (u16*)(ws + 47448064);     // 16777216
    u16* ha16    = (u16*)(ws + 64225280);     // 1048576  -> end 65273856

    hipLaunchKernelGGL(k_prep, dim3(6288), dim3(256), 0, stream,
                       mask, k_cache, v_cache, h_vlm, h_act,
                       cosT, sinT, maskS, K_all, V_all, hv16, ha16);
    hipLaunchKernelGGL(k_transpose6, dim3(3072), dim3(256), 0, stream,
                       Wk_vlm, WkvT, Wv_vlm, WvvT, Wk_act, WkaT, Wv_act, WvaT,
                       Wq_act, WqaT, Wo_act, WoT);
    hipLaunchKernelGGL(k_gemm_qkv, dim3(64, 10), dim3(256), 0, stream,
                       hv16, ha16, WkvT, WvvT, WqaT, WkaT, WvaT,
                       pos_vlm, pos_act, cosT, sinT, Qbuf, K_all, V_all);
    hipLaunchKernelGGL(k_attn_split, dim3(16, 4, NSPLIT), dim3(256), 0, stream,
                       Qbuf, K_all, V_all, maskS, po, pml);
    hipLaunchKernelGGL(k_attn_red, dim3(16, 4), dim3(256), 0, stream, po, pml, AO);
    hipLaunchKernelGGL(k_gemm_out, dim3(4, 32), dim3(256), 0, stream, AO, WoT, (float*)d_out);
}